// Round 4
// baseline (936.294 us; speedup 1.0000x reference)
//
#include <hip/hip_runtime.h>
#include <stdint.h>

#define B_   16
#define C_   192
#define TX_  512
#define TY_  2048
#define K_   384       // 2*C
#define SEG_ 32
#define NEG_INF_ (-1e9f)

// Output layout (floats) in d_out:
//   z_slice : [16,192,32]    @ 0         (98304)
//   ids     : [16] (as f32)  @ 98304     (16)
//   attn    : [16,2048,512]  @ 98320     (16777216)
//   m_p_a   : [16,192,2048]  @ 16875536  (6291456)
//   logs_p_a: [16,192,2048]  @ 23166992  (6291456)

// ---------------------------------------------------------------------------
// K0: build B-matrix [b, k, tx] (k<192: s = exp(-2 logs); k>=192: s*m_p) and
//     c_term[b,tx] = sum_c (-0.5 s m^2 - logs)
// ---------------------------------------------------------------------------
__global__ __launch_bounds__(128) void k_prep(const float* __restrict__ mp,
                                              const float* __restrict__ logsp,
                                              float* __restrict__ Bmat,
                                              float* __restrict__ cterm) {
    int b  = blockIdx.y;
    int tx = blockIdx.x * 128 + threadIdx.x;
    const float* mb = mp    + (size_t)b * C_ * TX_ + tx;
    const float* lb = logsp + (size_t)b * C_ * TX_ + tx;
    float* B0 = Bmat + (size_t)b * K_ * TX_ + tx;
    float acc = 0.f;
    for (int c = 0; c < C_; ++c) {
        float lg = lb[(size_t)c * TX_];
        float m  = mb[(size_t)c * TX_];
        float s  = expf(-2.f * lg);
        B0[(size_t)c * TX_]        = s;
        B0[(size_t)(C_ + c) * TX_] = s * m;
        acc += -0.5f * s * m * m - lg;
    }
    cterm[b * TX_ + tx] = acc;
}

// ---------------------------------------------------------------------------
// K1: neg_cent GEMM.  C[b, ty, tx] = sum_k A[b,k,ty]*B[b,k,tx] + cterm[b,tx]
//     A is derived on the fly from z_p: k<192 -> -0.5*z^2 ; k>=192 -> z.
//     128x128 tile, 256 threads, 8x8 accumulators/thread, K-block 16.
// ---------------------------------------------------------------------------
__global__ __launch_bounds__(256) void k_gemm(const float* __restrict__ zp,
                                              const float* __restrict__ Bmat,
                                              const float* __restrict__ cterm,
                                              float* __restrict__ ncout) {
    __shared__ float As[16][128];
    __shared__ float Bs[16][128];
    int b  = blockIdx.z;
    int m0 = blockIdx.y * 128;   // ty
    int n0 = blockIdx.x * 128;   // tx
    int tid = threadIdx.x;
    int tm = tid >> 4;           // 0..15
    int tn = tid & 15;           // 0..15
    const float* zpb = zp   + (size_t)b * C_ * TY_;
    const float* Bb  = Bmat + (size_t)b * K_ * TX_;

    float acc[8][8];
#pragma unroll
    for (int i = 0; i < 8; ++i)
#pragma unroll
        for (int j = 0; j < 8; ++j) acc[i][j] = 0.f;

    int lrow = tid >> 5;           // 0..7
    int lcol = (tid & 31) << 2;    // 0..124

    for (int k0 = 0; k0 < K_; k0 += 16) {
        int ksrc = (k0 < C_) ? k0 : (k0 - C_);
        const float* Ab = zpb + (size_t)(ksrc + lrow) * TY_ + m0 + lcol;
        float4 z0 = *(const float4*)Ab;
        float4 z1 = *(const float4*)(Ab + (size_t)8 * TY_);
        if (k0 < C_) {
            z0.x = -0.5f * z0.x * z0.x; z0.y = -0.5f * z0.y * z0.y;
            z0.z = -0.5f * z0.z * z0.z; z0.w = -0.5f * z0.w * z0.w;
            z1.x = -0.5f * z1.x * z1.x; z1.y = -0.5f * z1.y * z1.y;
            z1.z = -0.5f * z1.z * z1.z; z1.w = -0.5f * z1.w * z1.w;
        }
        const float* Bp = Bb + (size_t)(k0 + lrow) * TX_ + n0 + lcol;
        float4 w0 = *(const float4*)Bp;
        float4 w1 = *(const float4*)(Bp + (size_t)8 * TX_);

        __syncthreads();   // prior iteration's reads done before overwrite
        *(float4*)&As[lrow][lcol]     = z0;
        *(float4*)&As[lrow + 8][lcol] = z1;
        *(float4*)&Bs[lrow][lcol]     = w0;
        *(float4*)&Bs[lrow + 8][lcol] = w1;
        __syncthreads();

#pragma unroll
        for (int kk = 0; kk < 16; ++kk) {
            float4 a0 = *(const float4*)&As[kk][tm * 8];
            float4 a1 = *(const float4*)&As[kk][tm * 8 + 4];
            float4 b0 = *(const float4*)&Bs[kk][tn * 8];
            float4 b1 = *(const float4*)&Bs[kk][tn * 8 + 4];
            float a[8]  = {a0.x, a0.y, a0.z, a0.w, a1.x, a1.y, a1.z, a1.w};
            float bb[8] = {b0.x, b0.y, b0.z, b0.w, b1.x, b1.y, b1.z, b1.w};
#pragma unroll
            for (int i = 0; i < 8; ++i)
#pragma unroll
                for (int j = 0; j < 8; ++j)
                    acc[i][j] = fmaf(a[i], bb[j], acc[i][j]);
        }
    }

    float cadd[8];
#pragma unroll
    for (int j = 0; j < 8; ++j) cadd[j] = cterm[b * TX_ + n0 + tn * 8 + j];

#pragma unroll
    for (int i = 0; i < 8; ++i) {
        int row = m0 + tm * 8 + i;
        float* orow = ncout + ((size_t)b * TY_ + row) * TX_ + n0 + tn * 8;
        float4 o0, o1;
        o0.x = acc[i][0] + cadd[0]; o0.y = acc[i][1] + cadd[1];
        o0.z = acc[i][2] + cadd[2]; o0.w = acc[i][3] + cadd[3];
        o1.x = acc[i][4] + cadd[4]; o1.y = acc[i][5] + cadd[5];
        o1.z = acc[i][6] + cadd[6]; o1.w = acc[i][7] + cadd[7];
        *(float4*)orow       = o0;
        *(float4*)(orow + 4) = o1;
    }
}

// ---------------------------------------------------------------------------
// K2: fused DP forward + backward. One block (1 wave) per batch.
//
// Forward: 8 columns/lane in registers. No masking/clamping (validated r3:
// masked cols only propagate rightward; drift stays far below any real path
// value, so consulted dirn bits are identical).
//
// Staging: register-prefetch failed twice (r2: VGPR 76, r3: VGPR 80 vs 128
// declared buffer regs — compiler collapses the double buffer and loads run
// serially at ~250 cyc each). Now: __builtin_amdgcn_global_load_lds (no dest
// VGPRs, void intrinsic -> cannot be sunk/collapsed), 4-row groups (8 KiB),
// triple-buffered stage in LDS, prefetch distance 2, hand-placed partial
// s_waitcnt vmcnt(8) so 16 loads stay in flight across compute.
// LDS: 128 KiB dirs + 24 KiB stage = 152 KiB.
//
// dirn bits packed 8/lane/row, 4 rows per dword -> one ds_write_b32 per
// group; dword[(row>>2)*64 + lane] holds rows 4q..4q+3.
//
// Backward: lane 0 walks the path reading LDS bytes (8-row groups, 2-byte
// speculative window since idx decreases <=1 per row).
// ---------------------------------------------------------------------------
#define WAITVM8() __builtin_amdgcn_s_waitcnt(3960)   // lgkm=15,exp=7,vmcnt=8
#define WAITVM0() __builtin_amdgcn_s_waitcnt(3952)   // lgkm=15,exp=7,vmcnt=0

#define ISSUE4(g)                                                            \
    {                                                                        \
        const char* gp = base4 + (size_t)(g) * 8192 + lane * 16;             \
        char* lp = (char*)stage + ((g) % 3) * 8192;                          \
        _Pragma("unroll") for (int c = 0; c < 8; ++c)                        \
            __builtin_amdgcn_global_load_lds(                                \
                (const __attribute__((address_space(1))) void*)(gp + c * 1024), \
                (__attribute__((address_space(3))) void*)(lp + c * 1024),    \
                16, 0, 0);                                                   \
    }

#define PROCG4(g)                                                            \
    {                                                                        \
        const float* rowp = (const float*)(stage + ((g) % 3) * 8192);        \
        unsigned dw = 0u;                                                    \
        _Pragma("unroll") for (int r = 0; r < 4; ++r) {                      \
            float4 p0 = *(const float4*)(rowp + r * 512 + lane * 8);         \
            float4 p1 = *(const float4*)(rowp + r * 512 + lane * 8 + 4);     \
            float rc[8] = {p0.x, p0.y, p0.z, p0.w, p1.x, p1.y, p1.z, p1.w};  \
            float left = __shfl_up(v[7], 1);                                 \
            if (lane == 0) left = NEG_INF_;                                  \
            unsigned by = 0u;                                                \
            _Pragma("unroll") for (int k = 7; k >= 0; --k) {                 \
                float vs = (k == 0) ? left : v[k - 1];                       \
                if (vs > v[k]) by |= (1u << k);                              \
                v[k] = fmaxf(v[k], vs) + rc[k];                              \
            }                                                                \
            dw |= by << (8 * r);                                             \
        }                                                                    \
        sdirs32[(g) * 64 + lane] = dw;                                       \
    }

__global__ __launch_bounds__(64, 1) void k_dp(const float* __restrict__ nc,
                                              const int* __restrict__ xl,
                                              const int* __restrict__ yl,
                                              int* __restrict__ path) {
    extern __shared__ unsigned char sdirs[];   // 128 KiB dirs + 24 KiB stage
    unsigned* sdirs32    = (unsigned*)sdirs;
    unsigned char* stage = sdirs + 131072;
    int b    = blockIdx.x;
    int lane = threadIdx.x;
    int t_x  = xl[b];
    int t_y  = yl[b]; if (t_y > TY_) t_y = TY_;
    const char* base4 = (const char*)(nc + (size_t)b * TY_ * TX_);

    int col0 = lane * 8;
    float v[8];
#pragma unroll
    for (int k = 0; k < 8; ++k) v[k] = (col0 + k == 0) ? 0.f : NEG_INF_;

    int ng = (t_y + 3) >> 2;   // >= 256 since t_y >= 1024

    ISSUE4(0);
    ISSUE4(1);
    for (int g = 0; g < ng - 1; ++g) {
        WAITVM8();                           // group g's 8 loads complete
        __builtin_amdgcn_sched_barrier(0);   // no ds_read hoisting above wait
        PROCG4(g);
        if (g + 2 < ng) ISSUE4(g + 2);
    }
    WAITVM0();
    __builtin_amdgcn_sched_barrier(0);
    PROCG4(ng - 1);

    __syncthreads();   // LDS dirn bits visible

    int* pb = path + b * TY_;
    for (int j = t_y + lane; j < TY_; j += 64) pb[j] = -1;

    if (lane == 0) {
        int idx = t_x - 1;
        int j   = t_y - 1;
        while (j >= 0) {
            int n  = (j + 1 < 8) ? (j + 1) : 8;
            int bs = (idx - 7) >> 3; if (bs < 0) bs = 0;
            int b2 = bs + 1;         if (b2 > 63) b2 = 63;
            unsigned lo[8], hi[8];
#pragma unroll
            for (int r = 0; r < 8; ++r) {
                if (r < n) {
                    int jr = j - r;
                    int rb = (jr >> 2) * 256 + (jr & 3);
                    lo[r] = sdirs[rb + bs * 4];
                    hi[r] = sdirs[rb + b2 * 4];
                }
            }
#pragma unroll
            for (int r = 0; r < 8; ++r) {
                if (r < n) {
                    pb[j - r] = idx;
                    int Bi = idx >> 3;
                    unsigned byte = (Bi == bs) ? lo[r] : hi[r];
                    idx -= (int)((byte >> (idx & 7)) & 1u);
                }
            }
            j -= n;
        }
    }
}

// ---------------------------------------------------------------------------
// K4a: attn one-hot write (overwrites the neg_cent scratch region).
// ---------------------------------------------------------------------------
__global__ __launch_bounds__(256) void k_attn(const int* __restrict__ path,
                                              float* __restrict__ attn) {
    int i   = blockIdx.x * 256 + threadIdx.x;   // over B*TY*TX/4
    int tx0 = (i & 127) << 2;                   // TX/4 = 128
    int bty = i >> 7;                           // b*TY + ty
    int p   = path[bty];
    float4 o;
    o.x = (p == tx0)     ? 1.f : 0.f;
    o.y = (p == tx0 + 1) ? 1.f : 0.f;
    o.z = (p == tx0 + 2) ? 1.f : 0.f;
    o.w = (p == tx0 + 3) ? 1.f : 0.f;
    ((float4*)attn)[i] = o;
}

// ---------------------------------------------------------------------------
// K4b: m_p_a / logs_p_a gather: out[b,c,ty] = (path[ty]>=0) ? in[b,c,path] : 0
// ---------------------------------------------------------------------------
__global__ __launch_bounds__(256) void k_proj(const int* __restrict__ path,
                                              const float* __restrict__ mp,
                                              const float* __restrict__ logsp,
                                              float* __restrict__ mpa,
                                              float* __restrict__ logsa) {
    int i   = blockIdx.x * 256 + threadIdx.x;   // over B*C*TY/4
    int ty0 = (i & 511) << 2;                   // TY/4 = 512
    int bc  = i >> 9;                           // b*C + c
    int b   = bc / C_;
    const int4 p4 = *(const int4*)(path + b * TY_ + ty0);
    const float* mrow = mp    + (size_t)bc * TX_;
    const float* lrow = logsp + (size_t)bc * TX_;
    float4 mo, lo;
    mo.x = (p4.x >= 0) ? mrow[p4.x] : 0.f;  lo.x = (p4.x >= 0) ? lrow[p4.x] : 0.f;
    mo.y = (p4.y >= 0) ? mrow[p4.y] : 0.f;  lo.y = (p4.y >= 0) ? lrow[p4.y] : 0.f;
    mo.z = (p4.z >= 0) ? mrow[p4.z] : 0.f;  lo.z = (p4.z >= 0) ? lrow[p4.z] : 0.f;
    mo.w = (p4.w >= 0) ? mrow[p4.w] : 0.f;  lo.w = (p4.w >= 0) ? lrow[p4.w] : 0.f;
    ((float4*)mpa)[i]   = mo;
    ((float4*)logsa)[i] = lo;
}

// ---------------------------------------------------------------------------
// K4c: random segment slice of z + ids output (replicates ref f32 math).
// ---------------------------------------------------------------------------
__global__ __launch_bounds__(256) void k_slice(const float* __restrict__ z,
                                               const int* __restrict__ yl,
                                               const float* __restrict__ ru,
                                               float* __restrict__ zs,
                                               float* __restrict__ oid) {
    int b = blockIdx.x;
    int safe = yl[b]; if (safe > TY_) safe = TY_;
    int idsmax = safe - SEG_; if (idsmax < 0) idsmax = 0;
    int ids = (int)(ru[b] * ((float)idsmax + 1e-8f));
    int lim = safe - ids;
    for (int t = threadIdx.x; t < C_ * SEG_; t += 256) {
        int c = t >> 5, k = t & 31;
        zs[b * C_ * SEG_ + t] =
            (k < lim) ? z[((size_t)b * C_ + c) * TY_ + ids + k] : 0.f;
    }
    if (threadIdx.x == 0) oid[b] = (float)ids;
}

// ---------------------------------------------------------------------------
extern "C" void kernel_launch(void* const* d_in, const int* in_sizes, int n_in,
                              void* d_out, int out_size, void* d_ws, size_t ws_size,
                              hipStream_t stream) {
    const float* z     = (const float*)d_in[0];
    const float* zp    = (const float*)d_in[1];
    const float* mp    = (const float*)d_in[2];
    const float* logsp = (const float*)d_in[3];
    const int*   xl    = (const int*)d_in[4];
    const int*   yl    = (const int*)d_in[5];
    const float* ru    = (const float*)d_in[6];

    float* out     = (float*)d_out;
    float* o_zs    = out;                  // 98304
    float* o_ids   = out + 98304;          // 16
    float* o_attn  = out + 98320;          // 16777216 (also neg_cent scratch)
    float* o_mpa   = out + 16875536;       // 6291456
    float* o_logsa = out + 23166992;       // 6291456

    float* Bmat  = (float*)d_ws;                        // 3,145,728 f
    float* cterm = Bmat + (size_t)B_ * K_ * TX_;        // 8192 f
    int*   path  = (int*)(cterm + B_ * TX_);            // 32768 i32

    // allow 152 KiB dynamic LDS for the fused DP kernel (host-side, not a
    // stream op — safe under graph capture; idempotent, called every launch)
    hipFuncSetAttribute((const void*)k_dp,
                        hipFuncAttributeMaxDynamicSharedMemorySize,
                        131072 + 3 * 8192);

    hipLaunchKernelGGL(k_prep, dim3(TX_ / 128, B_), dim3(128), 0, stream,
                       mp, logsp, Bmat, cterm);
    hipLaunchKernelGGL(k_gemm, dim3(TX_ / 128, TY_ / 128, B_), dim3(256), 0, stream,
                       zp, Bmat, cterm, o_attn);
    hipLaunchKernelGGL(k_dp, dim3(B_), dim3(64), 131072 + 3 * 8192, stream,
                       o_attn, xl, yl, path);
    hipLaunchKernelGGL(k_attn, dim3(B_ * TY_ * TX_ / 4 / 256), dim3(256), 0, stream,
                       path, o_attn);
    hipLaunchKernelGGL(k_proj, dim3(B_ * C_ * TY_ / 4 / 256), dim3(256), 0, stream,
                       path, mp, logsp, o_mpa, o_logsa);
    hipLaunchKernelGGL(k_slice, dim3(B_), dim3(256), 0, stream,
                       z, yl, ru, o_zs, o_ids);
}

// Round 5
// 854.515 us; speedup vs baseline: 1.0957x; 1.0957x over previous
//
#include <hip/hip_runtime.h>
#include <stdint.h>

#define B_   16
#define C_   192
#define TX_  512
#define TY_  2048
#define K_   384       // 2*C
#define SEG_ 32
#define NEG_INF_ (-1e9f)

// Output layout (floats) in d_out:
//   z_slice : [16,192,32]    @ 0         (98304)
//   ids     : [16] (as f32)  @ 98304     (16)
//   attn    : [16,2048,512]  @ 98320     (16777216)
//   m_p_a   : [16,192,2048]  @ 16875536  (6291456)
//   logs_p_a: [16,192,2048]  @ 23166992  (6291456)

// ---------------------------------------------------------------------------
// K0: build B-matrix [b, k, tx] (k<192: s = exp(-2 logs); k>=192: s*m_p) and
//     c_term[b,tx] = sum_c (-0.5 s m^2 - logs)
// ---------------------------------------------------------------------------
__global__ __launch_bounds__(128) void k_prep(const float* __restrict__ mp,
                                              const float* __restrict__ logsp,
                                              float* __restrict__ Bmat,
                                              float* __restrict__ cterm) {
    int b  = blockIdx.y;
    int tx = blockIdx.x * 128 + threadIdx.x;
    const float* mb = mp    + (size_t)b * C_ * TX_ + tx;
    const float* lb = logsp + (size_t)b * C_ * TX_ + tx;
    float* B0 = Bmat + (size_t)b * K_ * TX_ + tx;
    float acc = 0.f;
    for (int c = 0; c < C_; ++c) {
        float lg = lb[(size_t)c * TX_];
        float m  = mb[(size_t)c * TX_];
        float s  = expf(-2.f * lg);
        B0[(size_t)c * TX_]        = s;
        B0[(size_t)(C_ + c) * TX_] = s * m;
        acc += -0.5f * s * m * m - lg;
    }
    cterm[b * TX_ + tx] = acc;
}

// ---------------------------------------------------------------------------
// K1: neg_cent GEMM.  C[b, ty, tx] = sum_k A[b,k,ty]*B[b,k,tx] + cterm[b,tx]
//     A is derived on the fly from z_p: k<192 -> -0.5*z^2 ; k>=192 -> z.
//     128x128 tile, 256 threads, 8x8 accumulators/thread, K-block 16.
// ---------------------------------------------------------------------------
__global__ __launch_bounds__(256) void k_gemm(const float* __restrict__ zp,
                                              const float* __restrict__ Bmat,
                                              const float* __restrict__ cterm,
                                              float* __restrict__ ncout) {
    __shared__ float As[16][128];
    __shared__ float Bs[16][128];
    int b  = blockIdx.z;
    int m0 = blockIdx.y * 128;   // ty
    int n0 = blockIdx.x * 128;   // tx
    int tid = threadIdx.x;
    int tm = tid >> 4;           // 0..15
    int tn = tid & 15;           // 0..15
    const float* zpb = zp   + (size_t)b * C_ * TY_;
    const float* Bb  = Bmat + (size_t)b * K_ * TX_;

    float acc[8][8];
#pragma unroll
    for (int i = 0; i < 8; ++i)
#pragma unroll
        for (int j = 0; j < 8; ++j) acc[i][j] = 0.f;

    int lrow = tid >> 5;           // 0..7
    int lcol = (tid & 31) << 2;    // 0..124

    for (int k0 = 0; k0 < K_; k0 += 16) {
        int ksrc = (k0 < C_) ? k0 : (k0 - C_);
        const float* Ab = zpb + (size_t)(ksrc + lrow) * TY_ + m0 + lcol;
        float4 z0 = *(const float4*)Ab;
        float4 z1 = *(const float4*)(Ab + (size_t)8 * TY_);
        if (k0 < C_) {
            z0.x = -0.5f * z0.x * z0.x; z0.y = -0.5f * z0.y * z0.y;
            z0.z = -0.5f * z0.z * z0.z; z0.w = -0.5f * z0.w * z0.w;
            z1.x = -0.5f * z1.x * z1.x; z1.y = -0.5f * z1.y * z1.y;
            z1.z = -0.5f * z1.z * z1.z; z1.w = -0.5f * z1.w * z1.w;
        }
        const float* Bp = Bb + (size_t)(k0 + lrow) * TX_ + n0 + lcol;
        float4 w0 = *(const float4*)Bp;
        float4 w1 = *(const float4*)(Bp + (size_t)8 * TX_);

        __syncthreads();   // prior iteration's reads done before overwrite
        *(float4*)&As[lrow][lcol]     = z0;
        *(float4*)&As[lrow + 8][lcol] = z1;
        *(float4*)&Bs[lrow][lcol]     = w0;
        *(float4*)&Bs[lrow + 8][lcol] = w1;
        __syncthreads();

#pragma unroll
        for (int kk = 0; kk < 16; ++kk) {
            float4 a0 = *(const float4*)&As[kk][tm * 8];
            float4 a1 = *(const float4*)&As[kk][tm * 8 + 4];
            float4 b0 = *(const float4*)&Bs[kk][tn * 8];
            float4 b1 = *(const float4*)&Bs[kk][tn * 8 + 4];
            float a[8]  = {a0.x, a0.y, a0.z, a0.w, a1.x, a1.y, a1.z, a1.w};
            float bb[8] = {b0.x, b0.y, b0.z, b0.w, b1.x, b1.y, b1.z, b1.w};
#pragma unroll
            for (int i = 0; i < 8; ++i)
#pragma unroll
                for (int j = 0; j < 8; ++j)
                    acc[i][j] = fmaf(a[i], bb[j], acc[i][j]);
        }
    }

    float cadd[8];
#pragma unroll
    for (int j = 0; j < 8; ++j) cadd[j] = cterm[b * TX_ + n0 + tn * 8 + j];

#pragma unroll
    for (int i = 0; i < 8; ++i) {
        int row = m0 + tm * 8 + i;
        float* orow = ncout + ((size_t)b * TY_ + row) * TX_ + n0 + tn * 8;
        float4 o0, o1;
        o0.x = acc[i][0] + cadd[0]; o0.y = acc[i][1] + cadd[1];
        o0.z = acc[i][2] + cadd[2]; o0.w = acc[i][3] + cadd[3];
        o1.x = acc[i][4] + cadd[4]; o1.y = acc[i][5] + cadd[5];
        o1.z = acc[i][6] + cadd[6]; o1.w = acc[i][7] + cadd[7];
        *(float4*)orow       = o0;
        *(float4*)(orow + 4) = o1;
    }
}

// ---------------------------------------------------------------------------
// K2: fused DP forward + backward — PRODUCER/CONSUMER version.
//
// History: single-wave self-prefetch failed 3x. r2/r3: compiler collapses
// register double-buffers (VGPR 76/80 vs 128 declared). r4: global_load_lds
// + hand vmcnt(8) defeated — consumer ds_reads alias the LDS-DMA writes so
// the compiler inserts s_waitcnt vmcnt(0) before them, draining the whole
// prefetch queue (581 us, + 711K LDS bank-conflict cycles from stride-32B
// ds_read_b128).
//
// Now: 4 waves/block. Waves 1-3 = producers: round-robin 4-row groups,
// plain float4 global loads -> ds_write into a 3-slot LDS ring. Latency is
// hidden by wave-level overlap (3 independent vmcnt chains), which the
// compiler cannot defeat. Wave 0 = consumer: runs the DP recurrence.
// Handshake: per-slot flag + consumed-counter via __hip_atomic load/store
// (acquire/release, workgroup scope) in LDS.
//
// Stage layout is transposed at write time so consumer reads are
// ds_read_b128 at lane*16B (conflict-free): slot row = 2 KiB, first 1 KiB
// holds cols[8L..8L+4) at 16L, second 1 KiB cols[8L+4..8L+8) at 1024+16L.
// Producer lane P writes its global float4 (cols 4P..4P+3) to
// (P&1)*1024 + (P>>1)*16, and (cols 256+4P..) to that +512. <=2-way bank
// aliasing (free per m136).
//
// Forward math: 8 cols/lane, no masking/clamping (validated r3: masked cols
// only propagate rightward; drift stays far below any real path value).
// dirn bits packed 8/lane/row, 4 rows/dword: dword[(row>>2)*64+lane].
//
// Backward: consumer lane 0 walks the path from LDS bytes (its own wave's
// prior ds_writes -> in-order, no barrier needed; producers exit early).
// ---------------------------------------------------------------------------
#define NSLOT_ 3

__global__ __launch_bounds__(256, 1) void k_dp(const float* __restrict__ nc,
                                               const int* __restrict__ xl,
                                               const int* __restrict__ yl,
                                               int* __restrict__ path) {
    extern __shared__ unsigned char sdirs[];   // 128K dirs | 24K ring | flags
    unsigned* sdirs32 = (unsigned*)sdirs;
    float*    stagef  = (float*)(sdirs + 131072);          // 3 slots * 2048 f
    unsigned* flags   = (unsigned*)(sdirs + 131072 + NSLOT_ * 8192);
    unsigned* cons_ctr = flags + NSLOT_;

    int b    = blockIdx.x;
    int tid  = threadIdx.x;
    int w    = tid >> 6;          // wave id 0..3
    int lane = tid & 63;
    int t_x  = xl[b];
    int t_y  = yl[b]; if (t_y > TY_) t_y = TY_;
    const float* ncb = nc + (size_t)b * TY_ * TX_;
    int ng = (t_y + 3) >> 2;      // 4-row groups, >=256

    if (tid < NSLOT_ + 1) flags[tid] = 0;
    __syncthreads();

    if (w != 0) {
        // ---------------- producers (waves 1..3) ----------------
        int a0off = ((lane & 1) * 256 + (lane >> 1) * 4);   // floats
        for (int g = w - 1; g < ng; g += 3) {
            // wait for ring slot (g%3) to be free: group g-3 consumed
            while ((int)__hip_atomic_load(cons_ctr, __ATOMIC_ACQUIRE,
                                          __HIP_MEMORY_SCOPE_WORKGROUP) < g - 2) {}
            int j0 = g * 4;
            const float4* r0 = (const float4*)(ncb + (size_t)(j0    ) * TX_);
            const float4* r1 = (const float4*)(ncb + (size_t)(j0 + 1) * TX_);
            const float4* r2 = (const float4*)(ncb + (size_t)(j0 + 2) * TX_);
            const float4* r3 = (const float4*)(ncb + (size_t)(j0 + 3) * TX_);
            float4 q00 = r0[lane], q01 = r0[64 + lane];
            float4 q10 = r1[lane], q11 = r1[64 + lane];
            float4 q20 = r2[lane], q21 = r2[64 + lane];
            float4 q30 = r3[lane], q31 = r3[64 + lane];
            float* sb = stagef + (g % NSLOT_) * 2048;
            *(float4*)(sb             + a0off)       = q00;
            *(float4*)(sb             + a0off + 128) = q01;
            *(float4*)(sb + 512       + a0off)       = q10;
            *(float4*)(sb + 512       + a0off + 128) = q11;
            *(float4*)(sb + 1024      + a0off)       = q20;
            *(float4*)(sb + 1024      + a0off + 128) = q21;
            *(float4*)(sb + 1536      + a0off)       = q30;
            *(float4*)(sb + 1536      + a0off + 128) = q31;
            if (lane == 0)
                __hip_atomic_store(&flags[g % NSLOT_], (unsigned)(g + 1),
                                   __ATOMIC_RELEASE, __HIP_MEMORY_SCOPE_WORKGROUP);
        }
        return;
    }

    // ---------------- consumer (wave 0) ----------------
    int col0 = lane * 8;
    float v[8];
#pragma unroll
    for (int k = 0; k < 8; ++k) v[k] = (col0 + k == 0) ? 0.f : NEG_INF_;

    for (int g = 0; g < ng; ++g) {
        while (__hip_atomic_load(&flags[g % NSLOT_], __ATOMIC_ACQUIRE,
                                 __HIP_MEMORY_SCOPE_WORKGROUP) != (unsigned)(g + 1)) {}
        const float* rowp = stagef + (g % NSLOT_) * 2048;
        unsigned dw = 0u;
#pragma unroll
        for (int r = 0; r < 4; ++r) {
            float4 p0 = *(const float4*)(rowp + r * 512 + lane * 4);
            float4 p1 = *(const float4*)(rowp + r * 512 + 256 + lane * 4);
            float rc[8] = {p0.x, p0.y, p0.z, p0.w, p1.x, p1.y, p1.z, p1.w};
            float left = __shfl_up(v[7], 1);
            if (lane == 0) left = NEG_INF_;
            unsigned by = 0u;
#pragma unroll
            for (int k = 7; k >= 0; --k) {
                float vs = (k == 0) ? left : v[k - 1];
                if (vs > v[k]) by |= (1u << k);
                v[k] = fmaxf(v[k], vs) + rc[k];
            }
            dw |= by << (8 * r);
        }
        sdirs32[g * 64 + lane] = dw;
        if (lane == 0)
            __hip_atomic_store(cons_ctr, (unsigned)(g + 1),
                               __ATOMIC_RELEASE, __HIP_MEMORY_SCOPE_WORKGROUP);
    }

    // ---------------- backward walk (consumer wave only) ----------------
    int* pb = path + b * TY_;
    for (int j = t_y + lane; j < TY_; j += 64) pb[j] = -1;

    if (lane == 0) {
        int idx = t_x - 1;
        int j   = t_y - 1;
        while (j >= 0) {
            int n  = (j + 1 < 8) ? (j + 1) : 8;
            int bs = (idx - 7) >> 3; if (bs < 0) bs = 0;
            int b2 = bs + 1;         if (b2 > 63) b2 = 63;
            unsigned lo[8], hi[8];
#pragma unroll
            for (int r = 0; r < 8; ++r) {
                if (r < n) {
                    int jr = j - r;
                    int rb = (jr >> 2) * 256 + (jr & 3);
                    lo[r] = sdirs[rb + bs * 4];
                    hi[r] = sdirs[rb + b2 * 4];
                }
            }
#pragma unroll
            for (int r = 0; r < 8; ++r) {
                if (r < n) {
                    pb[j - r] = idx;
                    int Bi = idx >> 3;
                    unsigned byte = (Bi == bs) ? lo[r] : hi[r];
                    idx -= (int)((byte >> (idx & 7)) & 1u);
                }
            }
            j -= n;
        }
    }
}

// ---------------------------------------------------------------------------
// K4a: attn one-hot write (overwrites the neg_cent scratch region).
// ---------------------------------------------------------------------------
__global__ __launch_bounds__(256) void k_attn(const int* __restrict__ path,
                                              float* __restrict__ attn) {
    int i   = blockIdx.x * 256 + threadIdx.x;   // over B*TY*TX/4
    int tx0 = (i & 127) << 2;                   // TX/4 = 128
    int bty = i >> 7;                           // b*TY + ty
    int p   = path[bty];
    float4 o;
    o.x = (p == tx0)     ? 1.f : 0.f;
    o.y = (p == tx0 + 1) ? 1.f : 0.f;
    o.z = (p == tx0 + 2) ? 1.f : 0.f;
    o.w = (p == tx0 + 3) ? 1.f : 0.f;
    ((float4*)attn)[i] = o;
}

// ---------------------------------------------------------------------------
// K4b: m_p_a / logs_p_a gather: out[b,c,ty] = (path[ty]>=0) ? in[b,c,path] : 0
// ---------------------------------------------------------------------------
__global__ __launch_bounds__(256) void k_proj(const int* __restrict__ path,
                                              const float* __restrict__ mp,
                                              const float* __restrict__ logsp,
                                              float* __restrict__ mpa,
                                              float* __restrict__ logsa) {
    int i   = blockIdx.x * 256 + threadIdx.x;   // over B*C*TY/4
    int ty0 = (i & 511) << 2;                   // TY/4 = 512
    int bc  = i >> 9;                           // b*C + c
    int b   = bc / C_;
    const int4 p4 = *(const int4*)(path + b * TY_ + ty0);
    const float* mrow = mp    + (size_t)bc * TX_;
    const float* lrow = logsp + (size_t)bc * TX_;
    float4 mo, lo;
    mo.x = (p4.x >= 0) ? mrow[p4.x] : 0.f;  lo.x = (p4.x >= 0) ? lrow[p4.x] : 0.f;
    mo.y = (p4.y >= 0) ? mrow[p4.y] : 0.f;  lo.y = (p4.y >= 0) ? lrow[p4.y] : 0.f;
    mo.z = (p4.z >= 0) ? mrow[p4.z] : 0.f;  lo.z = (p4.z >= 0) ? lrow[p4.z] : 0.f;
    mo.w = (p4.w >= 0) ? mrow[p4.w] : 0.f;  lo.w = (p4.w >= 0) ? lrow[p4.w] : 0.f;
    ((float4*)mpa)[i]   = mo;
    ((float4*)logsa)[i] = lo;
}

// ---------------------------------------------------------------------------
// K4c: random segment slice of z + ids output (replicates ref f32 math).
// ---------------------------------------------------------------------------
__global__ __launch_bounds__(256) void k_slice(const float* __restrict__ z,
                                               const int* __restrict__ yl,
                                               const float* __restrict__ ru,
                                               float* __restrict__ zs,
                                               float* __restrict__ oid) {
    int b = blockIdx.x;
    int safe = yl[b]; if (safe > TY_) safe = TY_;
    int idsmax = safe - SEG_; if (idsmax < 0) idsmax = 0;
    int ids = (int)(ru[b] * ((float)idsmax + 1e-8f));
    int lim = safe - ids;
    for (int t = threadIdx.x; t < C_ * SEG_; t += 256) {
        int c = t >> 5, k = t & 31;
        zs[b * C_ * SEG_ + t] =
            (k < lim) ? z[((size_t)b * C_ + c) * TY_ + ids + k] : 0.f;
    }
    if (threadIdx.x == 0) oid[b] = (float)ids;
}

// ---------------------------------------------------------------------------
extern "C" void kernel_launch(void* const* d_in, const int* in_sizes, int n_in,
                              void* d_out, int out_size, void* d_ws, size_t ws_size,
                              hipStream_t stream) {
    const float* z     = (const float*)d_in[0];
    const float* zp    = (const float*)d_in[1];
    const float* mp    = (const float*)d_in[2];
    const float* logsp = (const float*)d_in[3];
    const int*   xl    = (const int*)d_in[4];
    const int*   yl    = (const int*)d_in[5];
    const float* ru    = (const float*)d_in[6];

    float* out     = (float*)d_out;
    float* o_zs    = out;                  // 98304
    float* o_ids   = out + 98304;          // 16
    float* o_attn  = out + 98320;          // 16777216 (also neg_cent scratch)
    float* o_mpa   = out + 16875536;       // 6291456
    float* o_logsa = out + 23166992;       // 6291456

    float* Bmat  = (float*)d_ws;                        // 3,145,728 f
    float* cterm = Bmat + (size_t)B_ * K_ * TX_;        // 8192 f
    int*   path  = (int*)(cterm + B_ * TX_);            // 32768 i32

    const int dp_lds = 131072 + NSLOT_ * 8192 + 64;

    // allow >64 KiB dynamic LDS for the fused DP kernel (host-side, not a
    // stream op — safe under graph capture; idempotent, called every launch)
    hipFuncSetAttribute((const void*)k_dp,
                        hipFuncAttributeMaxDynamicSharedMemorySize, dp_lds);

    hipLaunchKernelGGL(k_prep, dim3(TX_ / 128, B_), dim3(128), 0, stream,
                       mp, logsp, Bmat, cterm);
    hipLaunchKernelGGL(k_gemm, dim3(TX_ / 128, TY_ / 128, B_), dim3(256), 0, stream,
                       zp, Bmat, cterm, o_attn);
    hipLaunchKernelGGL(k_dp, dim3(B_), dim3(256), dp_lds, stream,
                       o_attn, xl, yl, path);
    hipLaunchKernelGGL(k_attn, dim3(B_ * TY_ * TX_ / 4 / 256), dim3(256), 0, stream,
                       path, o_attn);
    hipLaunchKernelGGL(k_proj, dim3(B_ * C_ * TY_ / 4 / 256), dim3(256), 0, stream,
                       path, mp, logsp, o_mpa, o_logsa);
    hipLaunchKernelGGL(k_slice, dim3(B_), dim3(256), 0, stream,
                       z, yl, ru, o_zs, o_ids);
}

// Round 6
// 843.449 us; speedup vs baseline: 1.1101x; 1.0131x over previous
//
#include <hip/hip_runtime.h>
#include <stdint.h>

#define B_   16
#define C_   192
#define TX_  512
#define TY_  2048
#define K_   384       // 2*C
#define SEG_ 32
#define NEG_INF_ (-1e9f)

// Output layout (floats) in d_out:
//   z_slice : [16,192,32]    @ 0         (98304)
//   ids     : [16] (as f32)  @ 98304     (16)
//   attn    : [16,2048,512]  @ 98320     (16777216)
//   m_p_a   : [16,192,2048]  @ 16875536  (6291456)
//   logs_p_a: [16,192,2048]  @ 23166992  (6291456)

// ---------------------------------------------------------------------------
// K0: build B-matrix [b, k, tx] (k<192: s = exp(-2 logs); k>=192: s*m_p) and
//     c_term[b,tx] = sum_c (-0.5 s m^2 - logs)
// ---------------------------------------------------------------------------
__global__ __launch_bounds__(128) void k_prep(const float* __restrict__ mp,
                                              const float* __restrict__ logsp,
                                              float* __restrict__ Bmat,
                                              float* __restrict__ cterm) {
    int b  = blockIdx.y;
    int tx = blockIdx.x * 128 + threadIdx.x;
    const float* mb = mp    + (size_t)b * C_ * TX_ + tx;
    const float* lb = logsp + (size_t)b * C_ * TX_ + tx;
    float* B0 = Bmat + (size_t)b * K_ * TX_ + tx;
    float acc = 0.f;
    for (int c = 0; c < C_; ++c) {
        float lg = lb[(size_t)c * TX_];
        float m  = mb[(size_t)c * TX_];
        float s  = expf(-2.f * lg);
        B0[(size_t)c * TX_]        = s;
        B0[(size_t)(C_ + c) * TX_] = s * m;
        acc += -0.5f * s * m * m - lg;
    }
    cterm[b * TX_ + tx] = acc;
}

// ---------------------------------------------------------------------------
// K1: neg_cent GEMM.  C[b, ty, tx] = sum_k A[b,k,ty]*B[b,k,tx] + cterm[b,tx]
//     A is derived on the fly from z_p: k<192 -> -0.5*z^2 ; k>=192 -> z.
//     128x128 tile, 256 threads, 8x8 accumulators/thread, K-block 16.
// ---------------------------------------------------------------------------
__global__ __launch_bounds__(256) void k_gemm(const float* __restrict__ zp,
                                              const float* __restrict__ Bmat,
                                              const float* __restrict__ cterm,
                                              float* __restrict__ ncout) {
    __shared__ float As[16][128];
    __shared__ float Bs[16][128];
    int b  = blockIdx.z;
    int m0 = blockIdx.y * 128;   // ty
    int n0 = blockIdx.x * 128;   // tx
    int tid = threadIdx.x;
    int tm = tid >> 4;           // 0..15
    int tn = tid & 15;           // 0..15
    const float* zpb = zp   + (size_t)b * C_ * TY_;
    const float* Bb  = Bmat + (size_t)b * K_ * TX_;

    float acc[8][8];
#pragma unroll
    for (int i = 0; i < 8; ++i)
#pragma unroll
        for (int j = 0; j < 8; ++j) acc[i][j] = 0.f;

    int lrow = tid >> 5;           // 0..7
    int lcol = (tid & 31) << 2;    // 0..124

    for (int k0 = 0; k0 < K_; k0 += 16) {
        int ksrc = (k0 < C_) ? k0 : (k0 - C_);
        const float* Ab = zpb + (size_t)(ksrc + lrow) * TY_ + m0 + lcol;
        float4 z0 = *(const float4*)Ab;
        float4 z1 = *(const float4*)(Ab + (size_t)8 * TY_);
        if (k0 < C_) {
            z0.x = -0.5f * z0.x * z0.x; z0.y = -0.5f * z0.y * z0.y;
            z0.z = -0.5f * z0.z * z0.z; z0.w = -0.5f * z0.w * z0.w;
            z1.x = -0.5f * z1.x * z1.x; z1.y = -0.5f * z1.y * z1.y;
            z1.z = -0.5f * z1.z * z1.z; z1.w = -0.5f * z1.w * z1.w;
        }
        const float* Bp = Bb + (size_t)(k0 + lrow) * TX_ + n0 + lcol;
        float4 w0 = *(const float4*)Bp;
        float4 w1 = *(const float4*)(Bp + (size_t)8 * TX_);

        __syncthreads();   // prior iteration's reads done before overwrite
        *(float4*)&As[lrow][lcol]     = z0;
        *(float4*)&As[lrow + 8][lcol] = z1;
        *(float4*)&Bs[lrow][lcol]     = w0;
        *(float4*)&Bs[lrow + 8][lcol] = w1;
        __syncthreads();

#pragma unroll
        for (int kk = 0; kk < 16; ++kk) {
            float4 a0 = *(const float4*)&As[kk][tm * 8];
            float4 a1 = *(const float4*)&As[kk][tm * 8 + 4];
            float4 b0 = *(const float4*)&Bs[kk][tn * 8];
            float4 b1 = *(const float4*)&Bs[kk][tn * 8 + 4];
            float a[8]  = {a0.x, a0.y, a0.z, a0.w, a1.x, a1.y, a1.z, a1.w};
            float bb[8] = {b0.x, b0.y, b0.z, b0.w, b1.x, b1.y, b1.z, b1.w};
#pragma unroll
            for (int i = 0; i < 8; ++i)
#pragma unroll
                for (int j = 0; j < 8; ++j)
                    acc[i][j] = fmaf(a[i], bb[j], acc[i][j]);
        }
    }

    float cadd[8];
#pragma unroll
    for (int j = 0; j < 8; ++j) cadd[j] = cterm[b * TX_ + n0 + tn * 8 + j];

#pragma unroll
    for (int i = 0; i < 8; ++i) {
        int row = m0 + tm * 8 + i;
        float* orow = ncout + ((size_t)b * TY_ + row) * TX_ + n0 + tn * 8;
        float4 o0, o1;
        o0.x = acc[i][0] + cadd[0]; o0.y = acc[i][1] + cadd[1];
        o0.z = acc[i][2] + cadd[2]; o0.w = acc[i][3] + cadd[3];
        o1.x = acc[i][4] + cadd[4]; o1.y = acc[i][5] + cadd[5];
        o1.z = acc[i][6] + cadd[6]; o1.w = acc[i][7] + cadd[7];
        *(float4*)orow       = o0;
        *(float4*)(orow + 4) = o1;
    }
}

// ---------------------------------------------------------------------------
// K2: fused DP forward + backward — producer/consumer, DPP cross-lane.
//
// r5 lessons: (1) __shfl_up lowers to ds_bpermute (~120 cyc) ON the per-row
// serial chain -> replaced with DPP wave_shr:1 (VALU pipe, ~4 cyc); lane 0
// gets NEG_INF via the dpp 'old' operand. (2) producer write layout was
// 4-way bank-conflicted (392K conflict cycles) -> now granule-swizzled:
// producer lane P loads granules 2P/2P+1 of each row, writes both at
// lane*16B contiguous; consumer reads lane*16B contiguous b128. (3) flag
// polls were on the chain -> pre-issued (consumer prefetches next flag
// before processing; producers pre-read cons_ctr after publishing).
//
// 4 waves/block: wave 0 consumer (DP recurrence), waves 1-3 producers
// (4-row groups round-robin into a 3-slot LDS ring, plain float4 loads ->
// each producer has an independent vmcnt chain; wave-level overlap hides
// latency and the compiler can't defeat it).
//
// Forward math: 8 cols/lane, no masking/clamping (validated r3). dirn bits
// packed 8/lane/row, 4 rows/dword: dword[(row>>2)*64+lane].
// Backward: consumer lane 0 walks path from LDS (2-byte speculative window).
// ---------------------------------------------------------------------------
#define NSLOT_ 3

__global__ __launch_bounds__(256, 1) void k_dp(const float* __restrict__ nc,
                                               const int* __restrict__ xl,
                                               const int* __restrict__ yl,
                                               int* __restrict__ path) {
    extern __shared__ unsigned char sdirs[];   // 128K dirs | 24K ring | flags
    unsigned* sdirs32 = (unsigned*)sdirs;
    float*    stagef  = (float*)(sdirs + 131072);          // 3 slots * 2048 f
    unsigned* flags   = (unsigned*)(sdirs + 131072 + NSLOT_ * 8192);
    unsigned* cons_ctr = flags + NSLOT_;

    int b    = blockIdx.x;
    int tid  = threadIdx.x;
    int w    = tid >> 6;          // wave id 0..3
    int lane = tid & 63;
    int t_x  = xl[b];
    int t_y  = yl[b]; if (t_y > TY_) t_y = TY_;
    const float* ncb = nc + (size_t)b * TY_ * TX_;
    int ng = (t_y + 3) >> 2;      // 4-row groups, >=256

    if (tid < NSLOT_ + 1) flags[tid] = 0;
    __syncthreads();

    if (w != 0) {
        // ---------------- producers (waves 1..3) ----------------
        int cv = (int)__hip_atomic_load(cons_ctr, __ATOMIC_ACQUIRE,
                                        __HIP_MEMORY_SCOPE_WORKGROUP);
        for (int g = w - 1; g < ng; g += 3) {
            while (cv < g - 2) {                 // slot (g%3) free?
                __builtin_amdgcn_s_sleep(1);
                cv = (int)__hip_atomic_load(cons_ctr, __ATOMIC_ACQUIRE,
                                            __HIP_MEMORY_SCOPE_WORKGROUP);
            }
            int j0 = g * 4;
            float* sb = stagef + (g % NSLOT_) * 2048;
#pragma unroll
            for (int r = 0; r < 4; ++r) {
                const float4* row = (const float4*)(ncb + (size_t)(j0 + r) * TX_);
                float4 q0 = row[2 * lane];       // cols 8L..8L+3
                float4 q1 = row[2 * lane + 1];   // cols 8L+4..8L+7
                *(float4*)(sb + r * 512 + lane * 4)       = q0;
                *(float4*)(sb + r * 512 + 256 + lane * 4) = q1;
            }
            if (lane == 0)
                __hip_atomic_store(&flags[g % NSLOT_], (unsigned)(g + 1),
                                   __ATOMIC_RELEASE, __HIP_MEMORY_SCOPE_WORKGROUP);
            cv = (int)__hip_atomic_load(cons_ctr, __ATOMIC_ACQUIRE,
                                        __HIP_MEMORY_SCOPE_WORKGROUP);  // pre-poll
        }
        return;
    }

    // ---------------- consumer (wave 0) ----------------
    int col0 = lane * 8;
    float v[8];
#pragma unroll
    for (int k = 0; k < 8; ++k) v[k] = (col0 + k == 0) ? 0.f : NEG_INF_;

    const unsigned neg_bits = __float_as_uint(NEG_INF_);
    unsigned fv = 0;
    for (int g = 0; g < ng; ++g) {
        while (fv != (unsigned)(g + 1))
            fv = __hip_atomic_load(&flags[g % NSLOT_], __ATOMIC_ACQUIRE,
                                   __HIP_MEMORY_SCOPE_WORKGROUP);
        unsigned fnx = __hip_atomic_load(&flags[(g + 1) % NSLOT_], __ATOMIC_ACQUIRE,
                                         __HIP_MEMORY_SCOPE_WORKGROUP); // prefetch
        const float* rowp = stagef + (g % NSLOT_) * 2048;
        unsigned dw = 0u;
#pragma unroll
        for (int r = 0; r < 4; ++r) {
            float4 p0 = *(const float4*)(rowp + r * 512 + lane * 4);
            float4 p1 = *(const float4*)(rowp + r * 512 + 256 + lane * 4);
            float rc[8] = {p0.x, p0.y, p0.z, p0.w, p1.x, p1.y, p1.z, p1.w};
            // left neighbor's v[7] via DPP wave_shr:1 (VALU pipe, not LDS);
            // lane 0 gets 'old' = NEG_INF (bound_ctrl=false preserves old).
            float left = __uint_as_float(__builtin_amdgcn_update_dpp(
                (int)neg_bits, (int)__float_as_uint(v[7]),
                0x138 /*wave_shr:1*/, 0xF, 0xF, false));
            unsigned by = 0u;
#pragma unroll
            for (int k = 7; k >= 0; --k) {
                float vs = (k == 0) ? left : v[k - 1];
                if (vs > v[k]) by |= (1u << k);
                v[k] = fmaxf(v[k], vs) + rc[k];
            }
            dw |= by << (8 * r);
        }
        sdirs32[g * 64 + lane] = dw;
        if (lane == 0)
            __hip_atomic_store(cons_ctr, (unsigned)(g + 1),
                               __ATOMIC_RELEASE, __HIP_MEMORY_SCOPE_WORKGROUP);
        fv = fnx;
    }

    // ---------------- backward walk (consumer wave only) ----------------
    int* pb = path + b * TY_;
    for (int j = t_y + lane; j < TY_; j += 64) pb[j] = -1;

    if (lane == 0) {
        int idx = t_x - 1;
        int j   = t_y - 1;
        while (j >= 0) {
            int n  = (j + 1 < 8) ? (j + 1) : 8;
            int bs = (idx - 7) >> 3; if (bs < 0) bs = 0;
            int b2 = bs + 1;         if (b2 > 63) b2 = 63;
            unsigned lo[8], hi[8];
#pragma unroll
            for (int r = 0; r < 8; ++r) {
                if (r < n) {
                    int jr = j - r;
                    int rb = (jr >> 2) * 256 + (jr & 3);
                    lo[r] = sdirs[rb + bs * 4];
                    hi[r] = sdirs[rb + b2 * 4];
                }
            }
#pragma unroll
            for (int r = 0; r < 8; ++r) {
                if (r < n) {
                    pb[j - r] = idx;
                    int Bi = idx >> 3;
                    unsigned byte = (Bi == bs) ? lo[r] : hi[r];
                    idx -= (int)((byte >> (idx & 7)) & 1u);
                }
            }
            j -= n;
        }
    }
}

// ---------------------------------------------------------------------------
// K4a: attn one-hot write (overwrites the neg_cent scratch region).
// ---------------------------------------------------------------------------
__global__ __launch_bounds__(256) void k_attn(const int* __restrict__ path,
                                              float* __restrict__ attn) {
    int i   = blockIdx.x * 256 + threadIdx.x;   // over B*TY*TX/4
    int tx0 = (i & 127) << 2;                   // TX/4 = 128
    int bty = i >> 7;                           // b*TY + ty
    int p   = path[bty];
    float4 o;
    o.x = (p == tx0)     ? 1.f : 0.f;
    o.y = (p == tx0 + 1) ? 1.f : 0.f;
    o.z = (p == tx0 + 2) ? 1.f : 0.f;
    o.w = (p == tx0 + 3) ? 1.f : 0.f;
    ((float4*)attn)[i] = o;
}

// ---------------------------------------------------------------------------
// K4b: m_p_a / logs_p_a gather: out[b,c,ty] = (path[ty]>=0) ? in[b,c,path] : 0
// ---------------------------------------------------------------------------
__global__ __launch_bounds__(256) void k_proj(const int* __restrict__ path,
                                              const float* __restrict__ mp,
                                              const float* __restrict__ logsp,
                                              float* __restrict__ mpa,
                                              float* __restrict__ logsa) {
    int i   = blockIdx.x * 256 + threadIdx.x;   // over B*C*TY/4
    int ty0 = (i & 511) << 2;                   // TY/4 = 512
    int bc  = i >> 9;                           // b*C + c
    int b   = bc / C_;
    const int4 p4 = *(const int4*)(path + b * TY_ + ty0);
    const float* mrow = mp    + (size_t)bc * TX_;
    const float* lrow = logsp + (size_t)bc * TX_;
    float4 mo, lo;
    mo.x = (p4.x >= 0) ? mrow[p4.x] : 0.f;  lo.x = (p4.x >= 0) ? lrow[p4.x] : 0.f;
    mo.y = (p4.y >= 0) ? mrow[p4.y] : 0.f;  lo.y = (p4.y >= 0) ? lrow[p4.y] : 0.f;
    mo.z = (p4.z >= 0) ? mrow[p4.z] : 0.f;  lo.z = (p4.z >= 0) ? lrow[p4.z] : 0.f;
    mo.w = (p4.w >= 0) ? mrow[p4.w] : 0.f;  lo.w = (p4.w >= 0) ? lrow[p4.w] : 0.f;
    ((float4*)mpa)[i]   = mo;
    ((float4*)logsa)[i] = lo;
}

// ---------------------------------------------------------------------------
// K4c: random segment slice of z + ids output (replicates ref f32 math).
// ---------------------------------------------------------------------------
__global__ __launch_bounds__(256) void k_slice(const float* __restrict__ z,
                                               const int* __restrict__ yl,
                                               const float* __restrict__ ru,
                                               float* __restrict__ zs,
                                               float* __restrict__ oid) {
    int b = blockIdx.x;
    int safe = yl[b]; if (safe > TY_) safe = TY_;
    int idsmax = safe - SEG_; if (idsmax < 0) idsmax = 0;
    int ids = (int)(ru[b] * ((float)idsmax + 1e-8f));
    int lim = safe - ids;
    for (int t = threadIdx.x; t < C_ * SEG_; t += 256) {
        int c = t >> 5, k = t & 31;
        zs[b * C_ * SEG_ + t] =
            (k < lim) ? z[((size_t)b * C_ + c) * TY_ + ids + k] : 0.f;
    }
    if (threadIdx.x == 0) oid[b] = (float)ids;
}

// ---------------------------------------------------------------------------
extern "C" void kernel_launch(void* const* d_in, const int* in_sizes, int n_in,
                              void* d_out, int out_size, void* d_ws, size_t ws_size,
                              hipStream_t stream) {
    const float* z     = (const float*)d_in[0];
    const float* zp    = (const float*)d_in[1];
    const float* mp    = (const float*)d_in[2];
    const float* logsp = (const float*)d_in[3];
    const int*   xl    = (const int*)d_in[4];
    const int*   yl    = (const int*)d_in[5];
    const float* ru    = (const float*)d_in[6];

    float* out     = (float*)d_out;
    float* o_zs    = out;                  // 98304
    float* o_ids   = out + 98304;          // 16
    float* o_attn  = out + 98320;          // 16777216 (also neg_cent scratch)
    float* o_mpa   = out + 16875536;       // 6291456
    float* o_logsa = out + 23166992;       // 6291456

    float* Bmat  = (float*)d_ws;                        // 3,145,728 f
    float* cterm = Bmat + (size_t)B_ * K_ * TX_;        // 8192 f
    int*   path  = (int*)(cterm + B_ * TX_);            // 32768 i32

    const int dp_lds = 131072 + NSLOT_ * 8192 + 64;

    // allow >64 KiB dynamic LDS for the fused DP kernel (host-side, not a
    // stream op — safe under graph capture; idempotent, called every launch)
    hipFuncSetAttribute((const void*)k_dp,
                        hipFuncAttributeMaxDynamicSharedMemorySize, dp_lds);

    hipLaunchKernelGGL(k_prep, dim3(TX_ / 128, B_), dim3(128), 0, stream,
                       mp, logsp, Bmat, cterm);
    hipLaunchKernelGGL(k_gemm, dim3(TX_ / 128, TY_ / 128, B_), dim3(256), 0, stream,
                       zp, Bmat, cterm, o_attn);
    hipLaunchKernelGGL(k_dp, dim3(B_), dim3(256), dp_lds, stream,
                       o_attn, xl, yl, path);
    hipLaunchKernelGGL(k_attn, dim3(B_ * TY_ * TX_ / 4 / 256), dim3(256), 0, stream,
                       path, o_attn);
    hipLaunchKernelGGL(k_proj, dim3(B_ * C_ * TY_ / 4 / 256), dim3(256), 0, stream,
                       path, mp, logsp, o_mpa, o_logsa);
    hipLaunchKernelGGL(k_slice, dim3(B_), dim3(256), 0, stream,
                       z, yl, ru, o_zs, o_ids);
}

// Round 7
// 781.720 us; speedup vs baseline: 1.1977x; 1.0790x over previous
//
#include <hip/hip_runtime.h>
#include <stdint.h>

#define B_   16
#define C_   192
#define TX_  512
#define TY_  2048
#define K_   384       // 2*C
#define SEG_ 32
#define NEG_INF_ (-1e9f)

// Output layout (floats) in d_out:
//   z_slice : [16,192,32]    @ 0         (98304)
//   ids     : [16] (as f32)  @ 98304     (16)
//   attn    : [16,2048,512]  @ 98320     (16777216)
//   m_p_a   : [16,192,2048]  @ 16875536  (6291456)
//   logs_p_a: [16,192,2048]  @ 23166992  (6291456)

// ---------------------------------------------------------------------------
// K0: build B-matrix [b, k, tx] (k<192: s = exp(-2 logs); k>=192: s*m_p) and
//     c_term[b,tx] = sum_c (-0.5 s m^2 - logs)
// ---------------------------------------------------------------------------
__global__ __launch_bounds__(128) void k_prep(const float* __restrict__ mp,
                                              const float* __restrict__ logsp,
                                              float* __restrict__ Bmat,
                                              float* __restrict__ cterm) {
    int b  = blockIdx.y;
    int tx = blockIdx.x * 128 + threadIdx.x;
    const float* mb = mp    + (size_t)b * C_ * TX_ + tx;
    const float* lb = logsp + (size_t)b * C_ * TX_ + tx;
    float* B0 = Bmat + (size_t)b * K_ * TX_ + tx;
    float acc = 0.f;
    for (int c = 0; c < C_; ++c) {
        float lg = lb[(size_t)c * TX_];
        float m  = mb[(size_t)c * TX_];
        float s  = expf(-2.f * lg);
        B0[(size_t)c * TX_]        = s;
        B0[(size_t)(C_ + c) * TX_] = s * m;
        acc += -0.5f * s * m * m - lg;
    }
    cterm[b * TX_ + tx] = acc;
}

// ---------------------------------------------------------------------------
// K1: neg_cent GEMM.  C[b, ty, tx] = sum_k A[b,k,ty]*B[b,k,tx] + cterm[b,tx]
//     A is derived on the fly from z_p: k<192 -> -0.5*z^2 ; k>=192 -> z.
//     128x128 tile, 256 threads, 8x8 accumulators/thread, K-block 16.
// ---------------------------------------------------------------------------
__global__ __launch_bounds__(256) void k_gemm(const float* __restrict__ zp,
                                              const float* __restrict__ Bmat,
                                              const float* __restrict__ cterm,
                                              float* __restrict__ ncout) {
    __shared__ float As[16][128];
    __shared__ float Bs[16][128];
    int b  = blockIdx.z;
    int m0 = blockIdx.y * 128;   // ty
    int n0 = blockIdx.x * 128;   // tx
    int tid = threadIdx.x;
    int tm = tid >> 4;           // 0..15
    int tn = tid & 15;           // 0..15
    const float* zpb = zp   + (size_t)b * C_ * TY_;
    const float* Bb  = Bmat + (size_t)b * K_ * TX_;

    float acc[8][8];
#pragma unroll
    for (int i = 0; i < 8; ++i)
#pragma unroll
        for (int j = 0; j < 8; ++j) acc[i][j] = 0.f;

    int lrow = tid >> 5;           // 0..7
    int lcol = (tid & 31) << 2;    // 0..124

    for (int k0 = 0; k0 < K_; k0 += 16) {
        int ksrc = (k0 < C_) ? k0 : (k0 - C_);
        const float* Ab = zpb + (size_t)(ksrc + lrow) * TY_ + m0 + lcol;
        float4 z0 = *(const float4*)Ab;
        float4 z1 = *(const float4*)(Ab + (size_t)8 * TY_);
        if (k0 < C_) {
            z0.x = -0.5f * z0.x * z0.x; z0.y = -0.5f * z0.y * z0.y;
            z0.z = -0.5f * z0.z * z0.z; z0.w = -0.5f * z0.w * z0.w;
            z1.x = -0.5f * z1.x * z1.x; z1.y = -0.5f * z1.y * z1.y;
            z1.z = -0.5f * z1.z * z1.z; z1.w = -0.5f * z1.w * z1.w;
        }
        const float* Bp = Bb + (size_t)(k0 + lrow) * TX_ + n0 + lcol;
        float4 w0 = *(const float4*)Bp;
        float4 w1 = *(const float4*)(Bp + (size_t)8 * TX_);

        __syncthreads();   // prior iteration's reads done before overwrite
        *(float4*)&As[lrow][lcol]     = z0;
        *(float4*)&As[lrow + 8][lcol] = z1;
        *(float4*)&Bs[lrow][lcol]     = w0;
        *(float4*)&Bs[lrow + 8][lcol] = w1;
        __syncthreads();

#pragma unroll
        for (int kk = 0; kk < 16; ++kk) {
            float4 a0 = *(const float4*)&As[kk][tm * 8];
            float4 a1 = *(const float4*)&As[kk][tm * 8 + 4];
            float4 b0 = *(const float4*)&Bs[kk][tn * 8];
            float4 b1 = *(const float4*)&Bs[kk][tn * 8 + 4];
            float a[8]  = {a0.x, a0.y, a0.z, a0.w, a1.x, a1.y, a1.z, a1.w};
            float bb[8] = {b0.x, b0.y, b0.z, b0.w, b1.x, b1.y, b1.z, b1.w};
#pragma unroll
            for (int i = 0; i < 8; ++i)
#pragma unroll
                for (int j = 0; j < 8; ++j)
                    acc[i][j] = fmaf(a[i], bb[j], acc[i][j]);
        }
    }

    float cadd[8];
#pragma unroll
    for (int j = 0; j < 8; ++j) cadd[j] = cterm[b * TX_ + n0 + tn * 8 + j];

#pragma unroll
    for (int i = 0; i < 8; ++i) {
        int row = m0 + tm * 8 + i;
        float* orow = ncout + ((size_t)b * TY_ + row) * TX_ + n0 + tn * 8;
        float4 o0, o1;
        o0.x = acc[i][0] + cadd[0]; o0.y = acc[i][1] + cadd[1];
        o0.z = acc[i][2] + cadd[2]; o0.w = acc[i][3] + cadd[3];
        o1.x = acc[i][4] + cadd[4]; o1.y = acc[i][5] + cadd[5];
        o1.z = acc[i][6] + cadd[6]; o1.w = acc[i][7] + cadd[7];
        *(float4*)orow       = o0;
        *(float4*)(orow + 4) = o1;
    }
}

// ---------------------------------------------------------------------------
// K2: fused DP forward + backward — deep-ring producer/consumer.
//
// r6 lesson: ring depth 3 capped MLP at ~24 KB in flight/block -> 64 GB/s
// structural ceiling (matched measured 52). Fix: dirn bits go to a GLOBAL
// buffer (2 MB streamed byte-stores), freeing LDS for a 14-slot ring
// (112 KiB) + 7 producer waves. Producers run up to 14 groups ahead gated
// only by cons_ctr -> ~112 KB in flight/block; consumer becomes the limit.
//
// Block = 512 threads: wave 0 consumer (DP recurrence, DPP wave_shr:1 for
// the cross-lane term), waves 1..7 producers (4-row groups, g == w-1 mod 7,
// slot g mod 14; plain float4 loads -> granule-swizzled conflict-free
// ds_writes; independent per-wave vmcnt chains).
//
// Forward math: 8 cols/lane, no masking/clamping (validated r3). dirn bits:
// one byte per (row, lane) at gdirs[b][row*64 + lane] (4 byte-stores/group).
//
// Backward: 64-row batches; all 64 lanes fetch one full 64 B dirn strip
// each (uint4 x4) into a 4 KiB LDS window (one global round trip per 64
// rows), then lane 0 walks the batch with the 8-row lo/hi speculative
// scheme (idx decreases <=1/row).
// ---------------------------------------------------------------------------
#define NS_ 14    // ring slots
#define NP_ 7     // producer waves

__global__ __launch_bounds__(512, 1) void k_dp(const float* __restrict__ nc,
                                               const int* __restrict__ xl,
                                               const int* __restrict__ yl,
                                               int* __restrict__ path,
                                               unsigned char* __restrict__ gdirs) {
    extern __shared__ unsigned char slds[];   // NS_*8KiB ring | flags
    float*    stagef   = (float*)slds;
    unsigned* flags    = (unsigned*)(slds + NS_ * 8192);
    unsigned* cons_ctr = flags + NS_;

    int b    = blockIdx.x;
    int tid  = threadIdx.x;
    int w    = tid >> 6;          // wave id 0..7
    int lane = tid & 63;
    int t_x  = xl[b];
    int t_y  = yl[b]; if (t_y > TY_) t_y = TY_;
    const float* ncb = nc + (size_t)b * TY_ * TX_;
    unsigned char* gb = gdirs + (size_t)b * (TY_ * 64);
    int ng = (t_y + 3) >> 2;      // 4-row groups, >=256

    if (tid < NS_ + 1) flags[tid] = 0u;
    __syncthreads();

    if (w != 0) {
        // ---------------- producers (waves 1..7) ----------------
        int cv = (int)__hip_atomic_load(cons_ctr, __ATOMIC_ACQUIRE,
                                        __HIP_MEMORY_SCOPE_WORKGROUP);
        for (int g = w - 1; g < ng; g += NP_) {
            while (cv < g - (NS_ - 1)) {        // slot (g%NS_) free?
                __builtin_amdgcn_s_sleep(1);
                cv = (int)__hip_atomic_load(cons_ctr, __ATOMIC_ACQUIRE,
                                            __HIP_MEMORY_SCOPE_WORKGROUP);
            }
            int j0 = g * 4;
            float* sb = stagef + (g % NS_) * 2048;
#pragma unroll
            for (int r = 0; r < 4; ++r) {
                const float4* row = (const float4*)(ncb + (size_t)(j0 + r) * TX_);
                float4 q0 = row[2 * lane];       // cols 8L..8L+3
                float4 q1 = row[2 * lane + 1];   // cols 8L+4..8L+7
                *(float4*)(sb + r * 512 + lane * 4)       = q0;
                *(float4*)(sb + r * 512 + 256 + lane * 4) = q1;
            }
            if (lane == 0)
                __hip_atomic_store(&flags[g % NS_], (unsigned)(g + 1),
                                   __ATOMIC_RELEASE, __HIP_MEMORY_SCOPE_WORKGROUP);
            cv = (int)__hip_atomic_load(cons_ctr, __ATOMIC_ACQUIRE,
                                        __HIP_MEMORY_SCOPE_WORKGROUP);  // pre-poll
        }
        return;
    }

    // ---------------- consumer (wave 0) ----------------
    int col0 = lane * 8;
    float v[8];
#pragma unroll
    for (int k = 0; k < 8; ++k) v[k] = (col0 + k == 0) ? 0.f : NEG_INF_;

    const unsigned neg_bits = __float_as_uint(NEG_INF_);
    unsigned fv = 0;
    for (int g = 0; g < ng; ++g) {
        while (fv != (unsigned)(g + 1))
            fv = __hip_atomic_load(&flags[g % NS_], __ATOMIC_ACQUIRE,
                                   __HIP_MEMORY_SCOPE_WORKGROUP);
        unsigned fnx = __hip_atomic_load(&flags[(g + 1) % NS_], __ATOMIC_ACQUIRE,
                                         __HIP_MEMORY_SCOPE_WORKGROUP); // prefetch
        const float* rowp = stagef + (g % NS_) * 2048;
        unsigned dw = 0u;
#pragma unroll
        for (int r = 0; r < 4; ++r) {
            float4 p0 = *(const float4*)(rowp + r * 512 + lane * 4);
            float4 p1 = *(const float4*)(rowp + r * 512 + 256 + lane * 4);
            float rc[8] = {p0.x, p0.y, p0.z, p0.w, p1.x, p1.y, p1.z, p1.w};
            float left = __uint_as_float(__builtin_amdgcn_update_dpp(
                (int)neg_bits, (int)__float_as_uint(v[7]),
                0x138 /*wave_shr:1*/, 0xF, 0xF, false));
            unsigned by = 0u;
#pragma unroll
            for (int k = 7; k >= 0; --k) {
                float vs = (k == 0) ? left : v[k - 1];
                if (vs > v[k]) by |= (1u << k);
                v[k] = fmaxf(v[k], vs) + rc[k];
            }
            dw |= by << (8 * r);
        }
        int j0 = g * 4;
        gb[(size_t)(j0    ) * 64 + lane] = (unsigned char)(dw      );
        gb[(size_t)(j0 + 1) * 64 + lane] = (unsigned char)(dw >>  8);
        gb[(size_t)(j0 + 2) * 64 + lane] = (unsigned char)(dw >> 16);
        gb[(size_t)(j0 + 3) * 64 + lane] = (unsigned char)(dw >> 24);
        if (lane == 0)
            __hip_atomic_store(cons_ctr, (unsigned)(g + 1),
                               __ATOMIC_RELEASE, __HIP_MEMORY_SCOPE_WORKGROUP);
        fv = fnx;
    }

    // drain dirn byte-stores so our own backward loads see them
    __builtin_amdgcn_s_waitcnt(3952);   // vmcnt(0), lgkm=15, exp=7

    int* pb = path + b * TY_;
    for (int j2 = t_y + lane; j2 < TY_; j2 += 64) pb[j2] = -1;

    // ---------------- backward walk (wave 0 only) ----------------
    unsigned char* swin = (unsigned char*)stagef;   // 64 strips * 64 B = 4 KiB
    int j   = t_y - 1;
    int idx = t_x - 1;
    while (j >= 0) {
        int nb = (j + 1 < 64) ? (j + 1) : 64;
        if (lane < nb) {
            const uint4* rp = (const uint4*)(gb + (size_t)(j - lane) * 64);
            uint4 a0 = rp[0], a1 = rp[1], a2 = rp[2], a3 = rp[3];
            uint4* wp = (uint4*)(swin + lane * 64);
            wp[0] = a0; wp[1] = a1; wp[2] = a2; wp[3] = a3;
        }
        if (lane == 0) {
            int r2 = 0;
            while (r2 < nb) {
                int n = nb - r2; if (n > 8) n = 8;
                int Bhi = idx >> 3;
                int Blo = Bhi - 1; if (Blo < 0) Blo = 0;
                unsigned lo8[8], hi8[8];
#pragma unroll
                for (int r = 0; r < 8; ++r) {
                    if (r < n) {
                        lo8[r] = swin[(r2 + r) * 64 + Blo];
                        hi8[r] = swin[(r2 + r) * 64 + Bhi];
                    }
                }
#pragma unroll
                for (int r = 0; r < 8; ++r) {
                    if (r < n) {
                        pb[j - (r2 + r)] = idx;
                        unsigned byte = ((idx >> 3) == Bhi) ? hi8[r] : lo8[r];
                        idx -= (int)((byte >> (idx & 7)) & 1u);
                    }
                }
                r2 += n;
            }
        }
        j -= nb;
    }
}

// ---------------------------------------------------------------------------
// K4a: attn one-hot write (overwrites the neg_cent scratch region).
// ---------------------------------------------------------------------------
__global__ __launch_bounds__(256) void k_attn(const int* __restrict__ path,
                                              float* __restrict__ attn) {
    int i   = blockIdx.x * 256 + threadIdx.x;   // over B*TY*TX/4
    int tx0 = (i & 127) << 2;                   // TX/4 = 128
    int bty = i >> 7;                           // b*TY + ty
    int p   = path[bty];
    float4 o;
    o.x = (p == tx0)     ? 1.f : 0.f;
    o.y = (p == tx0 + 1) ? 1.f : 0.f;
    o.z = (p == tx0 + 2) ? 1.f : 0.f;
    o.w = (p == tx0 + 3) ? 1.f : 0.f;
    ((float4*)attn)[i] = o;
}

// ---------------------------------------------------------------------------
// K4b: m_p_a / logs_p_a gather: out[b,c,ty] = (path[ty]>=0) ? in[b,c,path] : 0
// ---------------------------------------------------------------------------
__global__ __launch_bounds__(256) void k_proj(const int* __restrict__ path,
                                              const float* __restrict__ mp,
                                              const float* __restrict__ logsp,
                                              float* __restrict__ mpa,
                                              float* __restrict__ logsa) {
    int i   = blockIdx.x * 256 + threadIdx.x;   // over B*C*TY/4
    int ty0 = (i & 511) << 2;                   // TY/4 = 512
    int bc  = i >> 9;                           // b*C + c
    int b   = bc / C_;
    const int4 p4 = *(const int4*)(path + b * TY_ + ty0);
    const float* mrow = mp    + (size_t)bc * TX_;
    const float* lrow = logsp + (size_t)bc * TX_;
    float4 mo, lo;
    mo.x = (p4.x >= 0) ? mrow[p4.x] : 0.f;  lo.x = (p4.x >= 0) ? lrow[p4.x] : 0.f;
    mo.y = (p4.y >= 0) ? mrow[p4.y] : 0.f;  lo.y = (p4.y >= 0) ? lrow[p4.y] : 0.f;
    mo.z = (p4.z >= 0) ? mrow[p4.z] : 0.f;  lo.z = (p4.z >= 0) ? lrow[p4.z] : 0.f;
    mo.w = (p4.w >= 0) ? mrow[p4.w] : 0.f;  lo.w = (p4.w >= 0) ? lrow[p4.w] : 0.f;
    ((float4*)mpa)[i]   = mo;
    ((float4*)logsa)[i] = lo;
}

// ---------------------------------------------------------------------------
// K4c: random segment slice of z + ids output (replicates ref f32 math).
// ---------------------------------------------------------------------------
__global__ __launch_bounds__(256) void k_slice(const float* __restrict__ z,
                                               const int* __restrict__ yl,
                                               const float* __restrict__ ru,
                                               float* __restrict__ zs,
                                               float* __restrict__ oid) {
    int b = blockIdx.x;
    int safe = yl[b]; if (safe > TY_) safe = TY_;
    int idsmax = safe - SEG_; if (idsmax < 0) idsmax = 0;
    int ids = (int)(ru[b] * ((float)idsmax + 1e-8f));
    int lim = safe - ids;
    for (int t = threadIdx.x; t < C_ * SEG_; t += 256) {
        int c = t >> 5, k = t & 31;
        zs[b * C_ * SEG_ + t] =
            (k < lim) ? z[((size_t)b * C_ + c) * TY_ + ids + k] : 0.f;
    }
    if (threadIdx.x == 0) oid[b] = (float)ids;
}

// ---------------------------------------------------------------------------
extern "C" void kernel_launch(void* const* d_in, const int* in_sizes, int n_in,
                              void* d_out, int out_size, void* d_ws, size_t ws_size,
                              hipStream_t stream) {
    const float* z     = (const float*)d_in[0];
    const float* zp    = (const float*)d_in[1];
    const float* mp    = (const float*)d_in[2];
    const float* logsp = (const float*)d_in[3];
    const int*   xl    = (const int*)d_in[4];
    const int*   yl    = (const int*)d_in[5];
    const float* ru    = (const float*)d_in[6];

    float* out     = (float*)d_out;
    float* o_zs    = out;                  // 98304
    float* o_ids   = out + 98304;          // 16
    float* o_attn  = out + 98320;          // 16777216 (also neg_cent scratch)
    float* o_mpa   = out + 16875536;       // 6291456
    float* o_logsa = out + 23166992;       // 6291456

    float*         Bmat  = (float*)d_ws;                     // 3,145,728 f
    float*         cterm = Bmat + (size_t)B_ * K_ * TX_;     // 8192 f
    int*           path  = (int*)(cterm + B_ * TX_);         // 32768 i32
    unsigned char* gdirs = (unsigned char*)(path + B_ * TY_); // 2 MB dirn bits

    const int dp_lds = NS_ * 8192 + 64;

    // allow >64 KiB dynamic LDS for the fused DP kernel (host-side, not a
    // stream op — safe under graph capture; idempotent, called every launch)
    hipFuncSetAttribute((const void*)k_dp,
                        hipFuncAttributeMaxDynamicSharedMemorySize, dp_lds);

    hipLaunchKernelGGL(k_prep, dim3(TX_ / 128, B_), dim3(128), 0, stream,
                       mp, logsp, Bmat, cterm);
    hipLaunchKernelGGL(k_gemm, dim3(TX_ / 128, TY_ / 128, B_), dim3(256), 0, stream,
                       zp, Bmat, cterm, o_attn);
    hipLaunchKernelGGL(k_dp, dim3(B_), dim3(512), dp_lds, stream,
                       o_attn, xl, yl, path, gdirs);
    hipLaunchKernelGGL(k_attn, dim3(B_ * TY_ * TX_ / 4 / 256), dim3(256), 0, stream,
                       path, o_attn);
    hipLaunchKernelGGL(k_proj, dim3(B_ * C_ * TY_ / 4 / 256), dim3(256), 0, stream,
                       path, mp, logsp, o_mpa, o_logsa);
    hipLaunchKernelGGL(k_slice, dim3(B_), dim3(256), 0, stream,
                       z, yl, ru, o_zs, o_ids);
}